// Round 8
// baseline (416.718 us; speedup 1.0000x reference)
//
#include <hip/hip_runtime.h>
#include <hip/hip_cooperative_groups.h>
#include <stdint.h>

namespace cg = cooperative_groups;

#define NR 16
#define NC 80
#define NA 8400
#define NB 16
#define KPRE 1024
#define MAXDET 300
#define CONF_T 0.25f
#define IOU_THR 0.45f
#define GRIDN 256
#define GRIDT (GRIDN * 256)
#define APAD 8448  // NA rounded to wave multiple (132*64) -> wave-uniform img

// Robust scalar read: harness passes python ints most likely as int32; fall
// back to float32 reinterpretation if the int pattern is implausible.
__device__ __forceinline__ float read_dim(const void* p) {
  int iv = *(const int*)p;
  return (iv > 0 && iv < (1 << 20)) ? (float)iv : *(const float*)p;
}

__device__ __forceinline__ const float* level_ptr(const float* p0, const float* p1,
                                                  const float* p2, int a, int& HW,
                                                  int& W, float& stride, int& m) {
  if (a < 6400)      { HW = 6400; W = 80; stride = 8.f;  m = a;        return p0; }
  else if (a < 8000) { HW = 1600; W = 40; stride = 16.f; m = a - 6400; return p1; }
  else               { HW = 400;  W = 20; stride = 32.f; m = a - 8000; return p2; }
}

__device__ __forceinline__ uint64_t readlane64(uint64_t v, int lane) {
  uint32_t lo = (uint32_t)__builtin_amdgcn_readlane((int)(uint32_t)v, lane);
  uint32_t hi = (uint32_t)__builtin_amdgcn_readlane((int)(uint32_t)(v >> 32), lane);
  return ((uint64_t)hi << 32) | lo;
}

// LDS is reused across phases (phases are separated by barriers).
union Smem {
  struct {  // phase 2: radix threshold. whist rows padded to 257 so the hot
            // bin of each wave-hist maps to a different bank (R7: 16 rows
            // 1024B apart -> same bank -> 16-way conflict on every atomic).
    uint32_t skeys[NA];
    uint32_t whist[4][257];
    uint32_t hsum[256], ssuf[256];
  } sel;                                    // 39760 B (max member)
  struct { uint64_t sk[2048]; } rank;       // 16384 B
  struct { float4 bb[KPRE]; } iou;          // 16384 B
  struct {
    float lsc[KPRE];
    uint64_t buf[2][16 * 65];
    int keepidx[MAXDET];
  } scan;                                   // 21936 B
};

__global__ __launch_bounds__(256) void k_mega(
    const float* __restrict__ p0, const float* __restrict__ p1,
    const float* __restrict__ p2, const void* __restrict__ hp,
    const void* __restrict__ wp, float4* __restrict__ boxes,
    uint32_t* __restrict__ keys, int* __restrict__ labels,
    uint64_t* __restrict__ cmp, int* __restrict__ ccount,
    int* __restrict__ tstar, float4* __restrict__ selbox,
    float4* __restrict__ selboff, float* __restrict__ selscore,
    int* __restrict__ sellab, uint64_t* __restrict__ rowmask,
    float* __restrict__ out) {
  cg::grid_group grid = cg::this_grid();
  __shared__ Smem sm;
  __shared__ int s_b1, s_rem, s_t16;
  int tid = threadIdx.x;
  int lane = tid & 63;
  int gtid = blockIdx.x * 256 + tid;

  // ---------------- P1: decode (4 threads/anchor, quad shuffles) -----------
  {
    float hx = read_dim(wp) - 1.f, hy = read_dim(hp) - 1.f;
    for (int wk = gtid; wk < NB * NA * 4; wk += GRIDT) {
      int aid = wk >> 2, k = wk & 3;
      int b = aid / NA, a = aid - b * NA;
      int HW, W, m; float stride;
      const float* p = level_ptr(p0, p1, p2, a, HW, W, stride, m);
      const float* base = p + (size_t)b * (4 * NR + NC) * HW + m;

      float v[NR]; float mx = -3.4e38f;
#pragma unroll
      for (int r = 0; r < NR; ++r) { v[r] = base[(size_t)(k * NR + r) * HW]; mx = fmaxf(mx, v[r]); }
      float se = 0.f, sn = 0.f;
#pragma unroll
      for (int r = 0; r < NR; ++r) { float e = expf(v[r] - mx); se += e; sn += e * (float)r; }
      float dk = sn / se * stride;

      float ml = -3.4e38f; int mc = NC;
#pragma unroll 4
      for (int c = 0; c < 20; ++c) {
        int ch = 4 * c + k;
        float vv = base[(size_t)(4 * NR + ch) * HW];
        if (vv > ml) { ml = vv; mc = ch; }
      }
#pragma unroll
      for (int off = 1; off < 4; off <<= 1) {
        float ov = __shfl_xor(ml, off);
        int oc = __shfl_xor(mc, off);
        if (ov > ml || (ov == ml && oc < mc)) { ml = ov; mc = oc; }
      }
      int bl = lane & ~3;
      float dl = __shfl(dk, bl), dt = __shfl(dk, bl + 1);
      float dr = __shfl(dk, bl + 2), db = __shfl(dk, bl + 3);

      if (k == 0) {
        int x = m % W, y = m / W;
        float cx = ((float)x + 0.5f) * stride, cy = ((float)y + 0.5f) * stride;
        boxes[aid] = make_float4(fminf(fmaxf(cx - dl, 0.f), hx),
                                 fminf(fmaxf(cy - dt, 0.f), hy),
                                 fminf(fmaxf(cx + dr, 0.f), hx),
                                 fminf(fmaxf(cy + db, 0.f), hy));
      } else if (k == 1) {
        float smax = 1.f / (1.f + expf(-ml));
        float s = smax > CONF_T ? smax : -1.0f;
        uint32_t bt = __float_as_uint(s);
        keys[aid] = (bt & 0x80000000u) ? ~bt : (bt | 0x80000000u);
      } else if (k == 2) {
        labels[aid] = mc;
      }
    }
  }
  grid.sync();

  // ---------------- P2: per-image radix threshold (blocks 0..15) -----------
  if (blockIdx.x < NB) {
    int img = blockIdx.x;
    int w4 = tid >> 6;
    const uint32_t* kb = keys + (size_t)img * NA;
    for (int j = tid; j < NA; j += 256) sm.sel.skeys[j] = kb[j];
    if (tid == 0) ccount[img] = 0;

    // pass 1: digit = key >> 24
    for (int j = tid; j < 4 * 257; j += 256) ((uint32_t*)sm.sel.whist)[j] = 0;
    __syncthreads();
    for (int j = tid; j < NA; j += 256) atomicAdd(&sm.sel.whist[w4][sm.sel.skeys[j] >> 24], 1u);
    __syncthreads();
    { uint32_t s = 0; for (int i = 0; i < 4; ++i) s += sm.sel.whist[i][tid]; sm.sel.hsum[tid] = s; }
    __syncthreads();
    { uint32_t s = 0; for (int j = tid; j < 256; ++j) s += sm.sel.hsum[j]; sm.sel.ssuf[tid] = s; }
    __syncthreads();
    {
      uint32_t ab = (tid == 255) ? 0u : sm.sel.ssuf[tid + 1];
      if (sm.sel.ssuf[tid] >= KPRE && ab < KPRE) { s_b1 = tid; s_rem = KPRE - (int)ab; }
    }
    __syncthreads();
    int b1 = s_b1, rem = s_rem;
    __syncthreads();

    // pass 2: digit = (key>>16)&0xFF restricted to (key>>24)==b1
    for (int j = tid; j < 4 * 257; j += 256) ((uint32_t*)sm.sel.whist)[j] = 0;
    __syncthreads();
    for (int j = tid; j < NA; j += 256) {
      uint32_t k = sm.sel.skeys[j];
      if ((int)(k >> 24) == b1) atomicAdd(&sm.sel.whist[w4][(k >> 16) & 0xFF], 1u);
    }
    __syncthreads();
    { uint32_t s = 0; for (int i = 0; i < 4; ++i) s += sm.sel.whist[i][tid]; sm.sel.hsum[tid] = s; }
    __syncthreads();
    { uint32_t s = 0; for (int j = tid; j < 256; ++j) s += sm.sel.hsum[j]; sm.sel.ssuf[tid] = s; }
    __syncthreads();
    {
      int ab = (tid == 255) ? 0 : (int)sm.sel.ssuf[tid + 1];
      if ((int)sm.sel.ssuf[tid] >= rem && ab < rem) s_t16 = (b1 << 8) | tid;
    }
    __syncthreads();
    if (tid == 0) tstar[img] = s_t16;
  }
  grid.sync();

  // ---------------- P3: grid-wide compact (wave-aggregated atomics) --------
  for (int wk = gtid; wk < NB * APAD; wk += GRIDT) {
    int img = wk / APAD;            // wave-uniform (APAD % 64 == 0)
    int a = wk - img * APAD;
    uint32_t k = 0; bool pass = false;
    if (a < NA) {
      k = keys[(size_t)img * NA + a];
      pass = (int)(k >> 16) >= tstar[img];
    }
    uint64_t mask = __ballot(pass);
    int pre = __popcll(mask & ((1ull << lane) - 1ull));
    int wc = __popcll(mask);
    int base = 0;
    if (lane == 0 && wc) base = atomicAdd(&ccount[img], wc);  // ~33/img total
    base = __shfl(base, 0);
    if (pass)
      cmp[(size_t)img * NA + base + pre] =
          ((uint64_t)k << 32) | (uint64_t)(0xFFFFFFFFu - (uint32_t)a);
  }
  grid.sync();

  // ---------------- P4: exact rank on top-M set (528 units) ----------------
  for (int u = blockIdx.x; u < NB * 33; u += GRIDN) {
    int img = u / 33, blk = u - img * 33;
    int M = ccount[img]; if (M > NA) M = NA;
    if (blk * 256 >= M) continue;  // uniform per block
    int c = blk * 256 + tid;
    uint64_t kc = (c < M) ? cmp[(size_t)img * NA + c] : 0;
    int rank = 0;
    for (int j0 = 0; j0 < M; j0 += 2048) {
      int nchunk = min(2048, M - j0);
      __syncthreads();
      for (int j = tid; j < nchunk; j += 256)
        sm.rank.sk[j] = cmp[(size_t)img * NA + j0 + j];
      __syncthreads();
      if (c < M) {
        int j = 0;
        for (; j + 4 <= nchunk; j += 4) {
          rank += (int)(sm.rank.sk[j] > kc) + (int)(sm.rank.sk[j + 1] > kc) +
                  (int)(sm.rank.sk[j + 2] > kc) + (int)(sm.rank.sk[j + 3] > kc);
        }
        for (; j < nchunk; ++j) rank += (int)(sm.rank.sk[j] > kc);
      }
    }
    __syncthreads();
    if (c < M && rank < KPRE) {
      int a = (int)(0xFFFFFFFFu - (uint32_t)kc);
      uint32_t uk = (uint32_t)(kc >> 32);
      uint32_t bits = (uk & 0x80000000u) ? (uk & 0x7FFFFFFFu) : ~uk;
      float s = __uint_as_float(bits);
      int lab = labels[img * NA + a];
      float4 bx = boxes[img * NA + a];
      float off = (float)lab * 4096.0f;  // replicate reference CLS_OFFSET fp math
      int o = img * KPRE + rank;
      selbox[o] = bx;
      selboff[o] = make_float4(bx.x + off, bx.y + off, bx.z + off, bx.w + off);
      selscore[o] = s;
      sellab[o] = lab;
    }
  }
  grid.sync();

  // ---------------- P5: IoU bitmask (256 units, transposed layout) ---------
  {
    int img = blockIdx.x >> 4, seg = blockIdx.x & 15;
    for (int j = tid; j < KPRE; j += 256) sm.iou.bb[j] = selboff[img * KPRE + j];
    __syncthreads();
#pragma unroll
    for (int t = 0; t < 4; ++t) {
      int pid = tid + t * 256;
      int row = seg * 64 + (pid >> 4);
      int w = pid & 15;
      float4 bi = sm.iou.bb[row];
      float ai = (bi.z - bi.x) * (bi.w - bi.y);
      uint64_t bits = 0;
      for (int jj = 0; jj < 64; ++jj) {
        int j = w * 64 + jj;
        float4 bj = sm.iou.bb[j];
        float lx = fmaxf(bi.x, bj.x), ly = fmaxf(bi.y, bj.y);
        float rx = fminf(bi.z, bj.z), ry = fminf(bi.w, bj.w);
        float iw = fmaxf(rx - lx, 0.f), ih = fmaxf(ry - ly, 0.f);
        float inter = iw * ih;
        float aj = (bj.z - bj.x) * (bj.w - bj.y);
        float iou = inter / (ai + aj - inter + 1e-7f);
        bits |= (uint64_t)((iou > IOU_THR) && (j != row)) << jj;
      }
      rowmask[(size_t)img * 16384 + (size_t)w * 1024 + row] = bits;
    }
  }
  grid.sync();

  // ---------------- P6: single-wave greedy scan (blocks 0..15, wave 0) -----
  if (blockIdx.x < NB && tid < 64) {
    int img = blockIdx.x;
    const uint64_t* g = rowmask + (size_t)img * 16384;
    for (int j = lane; j < KPRE; j += 64) sm.scan.lsc[j] = selscore[img * KPRE + j];

    {
      uint64_t r0[16];
#pragma unroll
      for (int t = 0; t < 16; ++t) r0[t] = g[t * 1024 + lane];
#pragma unroll
      for (int t = 0; t < 16; ++t) sm.scan.buf[0][t * 65 + lane] = r0[t];
    }
    asm volatile("" ::: "memory");

    uint64_t remv = 0;
    int n = 0;
    for (int c = 0; c < 16; ++c) {
      uint64_t rn[16];
      if (c + 1 < 16) {
#pragma unroll
        for (int t = 0; t < 16; ++t) rn[t] = g[t * 1024 + (c + 1) * 64 + lane];
      }
      const uint64_t* B = sm.scan.buf[c & 1];
      uint64_t m = B[c * 65 + lane];
      float sc = sm.scan.lsc[c * 64 + lane];
      uint64_t vmask = __ballot(sc > CONF_T);
      uint64_t cur = readlane64(remv, c);
      uint64_t kmask = 0;
#pragma unroll
      for (int ii = 0; ii < 64; ++ii) {
        if (((vmask >> ii) & 1ull) && !((cur >> ii) & 1ull)) {
          cur |= readlane64(m, ii);
          kmask |= (1ull << ii);
          if (lane == 0 && n < MAXDET) sm.scan.keepidx[n] = c * 64 + ii;
          n++;
        }
      }
      if (lane < 16) {
        uint64_t km = kmask;
        while (km) {
          int ii2 = __ffsll((unsigned long long)km) - 1;
          km &= km - 1;
          remv |= B[lane * 65 + ii2];
        }
      }
      if (!((vmask >> 63) & 1ull) || n >= MAXDET) break;
      if (c + 1 < 16) {
#pragma unroll
        for (int t = 0; t < 16; ++t) sm.scan.buf[(c + 1) & 1][t * 65 + lane] = rn[t];
      }
      asm volatile("" ::: "memory");
    }

    asm volatile("" ::: "memory");
    float* ob = out;                        // (B,300,4)
    float* os = out + NB * MAXDET * 4;      // (B,300)
    float* ol = out + NB * MAXDET * 5;      // labels as float
    float* ov = out + NB * MAXDET * 6;      // valid as 0/1 float
    int nk = n < MAXDET ? n : MAXDET;
    for (int s0 = 0; s0 < MAXDET; s0 += 64) {
      int slot = s0 + lane;
      if (slot >= MAXDET) break;
      bool v = slot < nk;
      float4 bx = make_float4(0.f, 0.f, 0.f, 0.f);
      float scv = 0.f, lbv = -1.f;
      if (v) {
        int i = sm.scan.keepidx[slot];
        bx = selbox[img * KPRE + i];
        scv = sm.scan.lsc[i];
        lbv = (float)sellab[img * KPRE + i];
      }
      ((float4*)ob)[img * MAXDET + slot] = bx;
      os[img * MAXDET + slot] = scv;
      ol[img * MAXDET + slot] = lbv;
      ov[img * MAXDET + slot] = v ? 1.0f : 0.0f;
    }
  }
}

// -------------------------------------------------------------- launcher ----
extern "C" void kernel_launch(void* const* d_in, const int* in_sizes, int n_in,
                              void* d_out, int out_size, void* d_ws, size_t ws_size,
                              hipStream_t stream) {
  const float* p0 = (const float*)d_in[0];
  const float* p1 = (const float*)d_in[1];
  const float* p2 = (const float*)d_in[2];
  const void* hp = d_in[3];
  const void* wp = d_in[4];

  // Workspace (~4.96 MB). rowmask ALIASES boxes: boxes is dead after P4's
  // gather; P5 (writer of rowmask) runs after a grid.sync.
  char* ws = (char*)d_ws;
  float4*   boxes    = (float4*)(ws + 0);          // 2150400
  uint64_t* rowmask  = (uint64_t*)(ws + 0);        // alias: 2097152
  uint32_t* keys     = (uint32_t*)(ws + 2150400);  // 537600
  int*      labels   = (int*)(ws + 2688000);       // 537600
  float4*   selbox   = (float4*)(ws + 3225600);    // 262144
  float4*   selboff  = (float4*)(ws + 3487744);    // 262144
  float*    selscore = (float*)(ws + 3749888);     // 65536
  int*      sellab   = (int*)(ws + 3815424);       // 65536
  int*      ccount   = (int*)(ws + 3880960);       // 64
  int*      tstar    = (int*)(ws + 3881024);       // 64
  uint64_t* cmp      = (uint64_t*)(ws + 3881088);  // 1075200 -> end 4956288
  float*    outp     = (float*)d_out;

  void* kargs[] = {&p0, &p1, &p2, &hp, &wp, &boxes, &keys, &labels,
                   &cmp, &ccount, &tstar, &selbox, &selboff, &selscore,
                   &sellab, &rowmask, &outp};
  hipLaunchCooperativeKernel(reinterpret_cast<void*>(k_mega), dim3(GRIDN),
                             dim3(256), kargs, 0, stream);
}

// Round 9
// 205.674 us; speedup vs baseline: 2.0261x; 2.0261x over previous
//
#include <hip/hip_runtime.h>
#include <stdint.h>

#define NR 16
#define NC 80
#define NA 8400
#define NB 16
#define KPRE 1024
#define MAXDET 300
#define CONF_T 0.25f
#define IOU_THR 0.45f

// Robust scalar read: harness passes python ints most likely as int32; fall
// back to float32 reinterpretation if the int pattern is implausible.
__device__ __forceinline__ float read_dim(const void* p) {
  int iv = *(const int*)p;
  return (iv > 0 && iv < (1 << 20)) ? (float)iv : *(const float*)p;
}

__device__ __forceinline__ const float* level_ptr(const float* p0, const float* p1,
                                                  const float* p2, int a, int& HW,
                                                  int& W, float& stride, int& m) {
  if (a < 6400)      { HW = 6400; W = 80; stride = 8.f;  m = a;        return p0; }
  else if (a < 8000) { HW = 1600; W = 40; stride = 16.f; m = a - 6400; return p1; }
  else               { HW = 400;  W = 20; stride = 32.f; m = a - 8000; return p2; }
}

__device__ __forceinline__ uint64_t readlane64(uint64_t v, int lane) {
  uint32_t lo = (uint32_t)__builtin_amdgcn_readlane((int)(uint32_t)v, lane);
  uint32_t hi = (uint32_t)__builtin_amdgcn_readlane((int)(uint32_t)(v >> 32), lane);
  return ((uint64_t)hi << 32) | lo;
}

// ---------------------------------------------------------------- decode ----
// 4 threads per anchor (quad): thread k owns DFL dim k (16 ch) + class
// channels ch%4==k (20 ch). 537600 threads = 8400 waves ~ 33 waves/CU.
// (R8 lesson: do NOT run this in a 256-block cooperative kernel — decode is
// latency-bound and needs the full wave oversubscription.)
__global__ __launch_bounds__(256) void k_decode(
    const float* __restrict__ p0, const float* __restrict__ p1,
    const float* __restrict__ p2, const void* __restrict__ hp,
    const void* __restrict__ wp, float4* __restrict__ boxes,
    uint32_t* __restrict__ keys, int* __restrict__ labels) {
  int gid = blockIdx.x * 256 + threadIdx.x;  // grid exactly NB*NA*4
  int aid = gid >> 2, k = gid & 3;
  int b = aid / NA, a = aid - b * NA;
  int HW, W, m; float stride;
  const float* p = level_ptr(p0, p1, p2, a, HW, W, stride, m);
  const float* base = p + (size_t)b * (4 * NR + NC) * HW + m;

  // DFL dim k: softmax-expectation over 16 bins
  float v[NR]; float mx = -3.4e38f;
#pragma unroll
  for (int r = 0; r < NR; ++r) { v[r] = base[(size_t)(k * NR + r) * HW]; mx = fmaxf(mx, v[r]); }
  float se = 0.f, sn = 0.f;
#pragma unroll
  for (int r = 0; r < NR; ++r) { float e = expf(v[r] - mx); se += e; sn += e * (float)r; }
  float dk = sn / se * stride;

  // class argmax over channels (4c + k), c=0..19 (raw logits; sigmoid monotone)
  float ml = -3.4e38f; int mc = NC;
#pragma unroll 4
  for (int c = 0; c < 20; ++c) {
    int ch = 4 * c + k;
    float vv = base[(size_t)(4 * NR + ch) * HW];
    if (vv > ml) { ml = vv; mc = ch; }
  }
  // quad reduce: strict max, tie -> smaller channel (reference first-argmax)
#pragma unroll
  for (int off = 1; off < 4; off <<= 1) {
    float ov = __shfl_xor(ml, off);
    int oc = __shfl_xor(mc, off);
    if (ov > ml || (ov == ml && oc < mc)) { ml = ov; mc = oc; }
  }
  // exchange the four DFL distances within the quad
  int lane = threadIdx.x & 63;
  int bl = lane & ~3;
  float dl = __shfl(dk, bl), dt = __shfl(dk, bl + 1);
  float dr = __shfl(dk, bl + 2), db = __shfl(dk, bl + 3);

  if (k == 0) {
    int x = m % W, y = m / W;
    float cx = ((float)x + 0.5f) * stride, cy = ((float)y + 0.5f) * stride;
    float hx = read_dim(wp) - 1.f, hy = read_dim(hp) - 1.f;
    boxes[aid] = make_float4(fminf(fmaxf(cx - dl, 0.f), hx),
                             fminf(fmaxf(cy - dt, 0.f), hy),
                             fminf(fmaxf(cx + dr, 0.f), hx),
                             fminf(fmaxf(cy + db, 0.f), hy));
  } else if (k == 1) {
    float smax = 1.f / (1.f + expf(-ml));
    float s = smax > CONF_T ? smax : -1.0f;
    uint32_t bt = __float_as_uint(s);
    keys[aid] = (bt & 0x80000000u) ? ~bt : (bt | 0x80000000u);  // sortable
  } else if (k == 2) {
    labels[aid] = mc;
  }
}

// ------------------------------- fused radix threshold + compact (per img) --
// R6 lesson: do NOT fuse the O(M^2) rank into this 16-block kernel.
// 16 per-wave hists (keys share hot top bytes; fewer hists serialize more).
__global__ __launch_bounds__(1024) void k_selcomp(const uint32_t* __restrict__ keys,
                                                  uint64_t* __restrict__ cmp,
                                                  int* __restrict__ ccount) {
  __shared__ __align__(16) uint32_t skeys[NA];  // 33600 B
  __shared__ uint32_t whist[16][256];           // 16 KB, one hist per wave
  __shared__ uint32_t hsum[256], ssuf[256];
  __shared__ int s_b1, s_rem, s_t16, s_cnt;
  int img = blockIdx.x, tid = threadIdx.x;
  int w = tid >> 6, lane = tid & 63;
  const uint4* kb4 = (const uint4*)(keys + (size_t)img * NA);  // NA/4 = 2100
  for (int j = tid; j < NA / 4; j += 1024) ((uint4*)skeys)[j] = kb4[j];
  if (tid == 0) s_cnt = 0;

  // ---- pass 1: digit = key >> 24 ----
  for (int j = tid; j < 16 * 256; j += 1024) ((uint32_t*)whist)[j] = 0;
  __syncthreads();
  for (int j = tid; j < NA; j += 1024) atomicAdd(&whist[w][skeys[j] >> 24], 1u);
  __syncthreads();
  if (tid < 256) { uint32_t s = 0; for (int i = 0; i < 16; ++i) s += whist[i][tid]; hsum[tid] = s; }
  __syncthreads();
  if (tid < 256) { uint32_t s = 0; for (int j = tid; j < 256; ++j) s += hsum[j]; ssuf[tid] = s; }
  __syncthreads();
  if (tid < 256) {
    uint32_t ab = (tid == 255) ? 0u : ssuf[tid + 1];
    if (ssuf[tid] >= KPRE && ab < KPRE) { s_b1 = tid; s_rem = KPRE - (int)ab; }
  }
  __syncthreads();
  int b1 = s_b1, rem = s_rem;
  __syncthreads();

  // ---- pass 2: digit = (key>>16)&0xFF restricted to (key>>24)==b1 ----
  for (int j = tid; j < 16 * 256; j += 1024) ((uint32_t*)whist)[j] = 0;
  __syncthreads();
  for (int j = tid; j < NA; j += 1024) {
    uint32_t k = skeys[j];
    if ((int)(k >> 24) == b1) atomicAdd(&whist[w][(k >> 16) & 0xFF], 1u);
  }
  __syncthreads();
  if (tid < 256) { uint32_t s = 0; for (int i = 0; i < 16; ++i) s += whist[i][tid]; hsum[tid] = s; }
  __syncthreads();
  if (tid < 256) { uint32_t s = 0; for (int j = tid; j < 256; ++j) s += hsum[j]; ssuf[tid] = s; }
  __syncthreads();
  if (tid < 256) {
    int ab = (tid == 255) ? 0 : (int)ssuf[tid + 1];
    if ((int)ssuf[tid] >= rem && ab < rem) s_t16 = (b1 << 8) | tid;
  }
  __syncthreads();
  uint32_t t16 = (uint32_t)s_t16;

  // ---- compact: wave-aggregated slot assignment via one LDS atomic/wave ----
  for (int j0 = 0; j0 < NA; j0 += 1024) {
    int j = j0 + tid;
    uint32_t k = (j < NA) ? skeys[j] : 0;
    bool pass = (j < NA) && ((k >> 16) >= t16);
    uint64_t mask = __ballot(pass);
    int pre = __popcll(mask & ((1ull << lane) - 1ull));
    int wc = __popcll(mask);
    int base = 0;
    if (lane == 0) base = wc ? atomicAdd(&s_cnt, wc) : 0;
    base = __shfl(base, 0);
    if (pass)
      cmp[(size_t)img * NA + base + pre] =
          ((uint64_t)k << 32) | (uint64_t)(0xFFFFFFFFu - (uint32_t)j);
  }
  __syncthreads();
  if (tid == 0) ccount[img] = s_cnt;
}

// ------------------------------------------------- exact rank on top-M set --
// Compacted set == exact top-M keys (upward-closed at bin granularity), so
// local rank == global rank. Winners gather their pre-decoded box (1 float4).
__global__ __launch_bounds__(256) void k_rank2(
    const uint64_t* __restrict__ cmp, const int* __restrict__ ccount,
    const float4* __restrict__ boxes, const int* __restrict__ labels,
    float4* __restrict__ selbox, float4* __restrict__ selboff,
    float* __restrict__ selscore, int* __restrict__ sellab) {
  __shared__ uint64_t sk[2048];
  int img = blockIdx.y;
  int M = ccount[img]; if (M > NA) M = NA;
  if (blockIdx.x * 256 >= M) return;  // uniform per block
  int c = blockIdx.x * 256 + threadIdx.x;
  uint64_t kc = (c < M) ? cmp[(size_t)img * NA + c] : 0;
  int rank = 0;
  for (int j0 = 0; j0 < M; j0 += 2048) {
    int nchunk = min(2048, M - j0);
    __syncthreads();
    for (int j = threadIdx.x; j < nchunk; j += 256)
      sk[j] = cmp[(size_t)img * NA + j0 + j];
    __syncthreads();
    if (c < M) {
      int j = 0;
      for (; j + 4 <= nchunk; j += 4) {
        rank += (int)(sk[j] > kc) + (int)(sk[j + 1] > kc) +
                (int)(sk[j + 2] > kc) + (int)(sk[j + 3] > kc);
      }
      for (; j < nchunk; ++j) rank += (int)(sk[j] > kc);
    }
  }
  if (c < M && rank < KPRE) {
    int a = (int)(0xFFFFFFFFu - (uint32_t)kc);
    uint32_t uk = (uint32_t)(kc >> 32);
    uint32_t bits = (uk & 0x80000000u) ? (uk & 0x7FFFFFFFu) : ~uk;
    float s = __uint_as_float(bits);
    int lab = labels[img * NA + a];
    float4 bx = boxes[img * NA + a];
    float off = (float)lab * 4096.0f;  // replicate reference CLS_OFFSET fp math
    int o = img * KPRE + rank;
    selbox[o] = bx;
    selboff[o] = make_float4(bx.x + off, bx.y + off, bx.z + off, bx.w + off);
    selscore[o] = s;
    sellab[o] = lab;
  }
}

// ----------------------------------------------------- IoU suppression bits -
// Output layout TRANSPOSED: rowmask[img][w][i] (w=word 0..15, i=row 0..1023)
// so k_scan's per-chunk staging loads are coalesced.
// Inner loop rotated per wave-quarter: the 4 concurrent bb[] b128 reads in a
// wave are 1024 B apart (same bank). jb = (jj + (w&3)) & 63 puts them on
// disjoint 4-bank spans -> conflict-free (R8 PMC: 1.6e7 conflict cycles).
__global__ __launch_bounds__(256) void k_iou(const float4* __restrict__ selboff,
                                             uint64_t* __restrict__ rowmask) {
  __shared__ float4 bb[KPRE];
  int img = blockIdx.y;
  for (int j = threadIdx.x; j < KPRE; j += 256) bb[j] = selboff[img * KPRE + j];
  __syncthreads();
  int i = blockIdx.x * 16 + (threadIdx.x & 15);
  int w = threadIdx.x >> 4;
  int rot = w & 3;
  float4 bi = bb[i];
  float ai = (bi.z - bi.x) * (bi.w - bi.y);
  uint64_t bits = 0;
  for (int jj = 0; jj < 64; ++jj) {
    int jb = (jj + rot) & 63;
    int j = w * 64 + jb;
    float4 bj = bb[j];
    float lx = fmaxf(bi.x, bj.x), ly = fmaxf(bi.y, bj.y);
    float rx = fminf(bi.z, bj.z), ry = fminf(bi.w, bj.w);
    float iw = fmaxf(rx - lx, 0.f), ih = fmaxf(ry - ly, 0.f);
    float inter = iw * ih;
    float aj = (bj.z - bj.x) * (bj.w - bj.y);
    float iou = inter / (ai + aj - inter + 1e-7f);
    bits |= (uint64_t)((iou > IOU_THR) && (j != i)) << jb;
  }
  rowmask[(size_t)img * 16384 + (size_t)w * 1024 + i] = bits;
}

// --------------------------- single-wave barrier-free greedy scan (SALU) ----
__global__ __launch_bounds__(64) void k_scan(
    const uint64_t* __restrict__ rowmask, const float4* __restrict__ selbox,
    const float* __restrict__ selscore, const int* __restrict__ sellab,
    float* __restrict__ out) {
  __shared__ float lsc[KPRE];
  __shared__ uint64_t buf[2][16 * 65];  // [w*65+ii], pad avoids bank conflicts
  __shared__ int keepidx[MAXDET];
  int img = blockIdx.x, lane = threadIdx.x;
  const uint64_t* g = rowmask + (size_t)img * 16384;

  for (int j = lane; j < KPRE; j += 64) lsc[j] = selscore[img * KPRE + j];

  // stage chunk 0
  {
    uint64_t r0[16];
#pragma unroll
    for (int t = 0; t < 16; ++t) r0[t] = g[t * 1024 + lane];
#pragma unroll
    for (int t = 0; t < 16; ++t) buf[0][t * 65 + lane] = r0[t];
  }
  asm volatile("" ::: "memory");

  uint64_t remv = 0;
  int n = 0;
  for (int c = 0; c < 16; ++c) {
    uint64_t rn[16];
    if (c + 1 < 16) {  // prefetch next chunk (global, overlapped with scan)
#pragma unroll
      for (int t = 0; t < 16; ++t) rn[t] = g[t * 1024 + (c + 1) * 64 + lane];
    }
    const uint64_t* B = buf[c & 1];
    uint64_t m = B[c * 65 + lane];           // self-chunk word of row `lane`
    float sc = lsc[c * 64 + lane];
    uint64_t vmask = __ballot(sc > CONF_T);  // valid (conf-passing) bitmap
    uint64_t cur = readlane64(remv, c);      // suppressed word for this chunk
    uint64_t kmask = 0;
#pragma unroll
    for (int ii = 0; ii < 64; ++ii) {
      if (((vmask >> ii) & 1ull) && !((cur >> ii) & 1ull)) {
        cur |= readlane64(m, ii);
        kmask |= (1ull << ii);
        if (lane == 0 && n < MAXDET) keepidx[n] = c * 64 + ii;
        n++;
      }
    }
    // batch remv update for future chunks (off the serial critical path)
    if (lane < 16) {
      uint64_t km = kmask;
      while (km) {
        int ii2 = __ffsll((unsigned long long)km) - 1;
        km &= km - 1;
        remv |= B[lane * 65 + ii2];
      }
    }
    // stop: last candidate of chunk invalid => all later invalid (sorted)
    if (!((vmask >> 63) & 1ull) || n >= MAXDET) break;
    if (c + 1 < 16) {
#pragma unroll
      for (int t = 0; t < 16; ++t) buf[(c + 1) & 1][t * 65 + lane] = rn[t];
    }
    asm volatile("" ::: "memory");
  }

  // parallel output pass
  asm volatile("" ::: "memory");
  float* ob = out;                        // (B,300,4)
  float* os = out + NB * MAXDET * 4;      // (B,300)
  float* ol = out + NB * MAXDET * 5;      // labels as float
  float* ov = out + NB * MAXDET * 6;      // valid as 0/1 float
  int nk = n < MAXDET ? n : MAXDET;
  for (int s0 = 0; s0 < MAXDET; s0 += 64) {
    int slot = s0 + lane;
    if (slot >= MAXDET) break;
    bool v = slot < nk;
    float4 bx = make_float4(0.f, 0.f, 0.f, 0.f);
    float scv = 0.f, lbv = -1.f;
    if (v) {
      int i = keepidx[slot];
      bx = selbox[img * KPRE + i];
      scv = lsc[i];
      lbv = (float)sellab[img * KPRE + i];
    }
    ((float4*)ob)[img * MAXDET + slot] = bx;
    os[img * MAXDET + slot] = scv;
    ol[img * MAXDET + slot] = lbv;
    ov[img * MAXDET + slot] = v ? 1.0f : 0.0f;
  }
}

// -------------------------------------------------------------- launcher ----
extern "C" void kernel_launch(void* const* d_in, const int* in_sizes, int n_in,
                              void* d_out, int out_size, void* d_ws, size_t ws_size,
                              hipStream_t stream) {
  const float* p0 = (const float*)d_in[0];
  const float* p1 = (const float*)d_in[1];
  const float* p2 = (const float*)d_in[2];
  const void* hp = d_in[3];
  const void* wp = d_in[4];

  // Workspace (~4.96 MB). rowmask ALIASES boxes: boxes is dead after
  // k_rank2's gather; k_iou (writer of rowmask) runs strictly after.
  char* ws = (char*)d_ws;
  float4*   boxes    = (float4*)(ws + 0);          // 2150400
  uint64_t* rowmask  = (uint64_t*)(ws + 0);        // alias: 2097152
  uint32_t* keys     = (uint32_t*)(ws + 2150400);  // 537600
  int*      labels   = (int*)(ws + 2688000);       // 537600
  float4*   selbox   = (float4*)(ws + 3225600);    // 262144
  float4*   selboff  = (float4*)(ws + 3487744);    // 262144
  float*    selscore = (float*)(ws + 3749888);     // 65536
  int*      sellab   = (int*)(ws + 3815424);       // 65536
  int*      ccount   = (int*)(ws + 3880960);       // 64
  uint64_t* cmp      = (uint64_t*)(ws + 3881024);  // 1075200 -> end 4956224

  k_decode<<<(NB * NA * 4) / 256, 256, 0, stream>>>(p0, p1, p2, hp, wp,
                                                    boxes, keys, labels);
  k_selcomp<<<NB, 1024, 0, stream>>>(keys, cmp, ccount);
  dim3 rg((NA + 255) / 256, NB);
  k_rank2<<<rg, 256, 0, stream>>>(cmp, ccount, boxes, labels,
                                  selbox, selboff, selscore, sellab);
  dim3 ig(KPRE / 16, NB);
  k_iou<<<ig, 256, 0, stream>>>(selboff, rowmask);
  k_scan<<<NB, 64, 0, stream>>>(rowmask, selbox, selscore, sellab,
                                (float*)d_out);
}